// Round 1
// baseline (148.586 us; speedup 1.0000x reference)
//
#include <hip/hip_runtime.h>

// ---------------------------------------------------------------------------
// Fused: GroupNorm -> QKV (1x1 conv) -> 8-head attention (n=1024,d=64)
//        -> proj (1x1 conv) + bias + residual(xn)
// b=8, c=512, n=h*w=1024, GROUPS=8 (64 ch/group), HEADS=8, dim_head=64
// All matmuls in bf16 MFMA 16x16x32, fp32 accum.
// ---------------------------------------------------------------------------

typedef short bf16x8 __attribute__((ext_vector_type(8)));
typedef float f32x4 __attribute__((ext_vector_type(4)));

#define MFMA16(a, b, c) __builtin_amdgcn_mfma_f32_16x16x32_bf16(a, b, c, 0, 0, 0)

__device__ __forceinline__ unsigned short f2bf(float f) {
    unsigned u = __float_as_uint(f);
    u += 0x7fffu + ((u >> 16) & 1u);   // round-to-nearest-even
    return (unsigned short)(u >> 16);
}

// ---------------- K0: convert weights fp32 -> bf16 -------------------------
__global__ __launch_bounds__(256) void cvt_weights(
    const float* __restrict__ wq, const float* __restrict__ wo,
    unsigned short* __restrict__ wqb, unsigned short* __restrict__ wob) {
    int i = blockIdx.x * 256 + threadIdx.x;   // 0..196607 (= 786432/4)
    {
        float4 v = reinterpret_cast<const float4*>(wq)[i];
        unsigned short* d = wqb + (size_t)i * 4;
        d[0] = f2bf(v.x); d[1] = f2bf(v.y); d[2] = f2bf(v.z); d[3] = f2bf(v.w);
    }
    if (i < 65536) {                          // 262144/4
        float4 v = reinterpret_cast<const float4*>(wo)[i];
        unsigned short* d = wob + (size_t)i * 4;
        d[0] = f2bf(v.x); d[1] = f2bf(v.y); d[2] = f2bf(v.z); d[3] = f2bf(v.w);
    }
}

// ---------------- K1: groupnorm stats (mean, rstd) per (b,group) ------------
__global__ __launch_bounds__(256) void gn_stats(
    const float* __restrict__ x, float2* __restrict__ stats) {
    __shared__ float ss[256], sq[256];
    int bg = blockIdx.x, t = threadIdx.x;
    const float4* p = reinterpret_cast<const float4*>(x + (size_t)bg * 65536);
    float s = 0.f, q = 0.f;
    for (int i = t; i < 16384; i += 256) {
        float4 v = p[i];
        s += v.x + v.y + v.z + v.w;
        q += v.x * v.x + v.y * v.y + v.z * v.z + v.w * v.w;
    }
    ss[t] = s; sq[t] = q; __syncthreads();
    for (int o = 128; o > 0; o >>= 1) {
        if (t < o) { ss[t] += ss[t + o]; sq[t] += sq[t + o]; }
        __syncthreads();
    }
    if (t == 0) {
        float mean = ss[0] * (1.f / 65536.f);
        float var  = sq[0] * (1.f / 65536.f) - mean * mean;
        stats[bg] = make_float2(mean, rsqrtf(var + 1e-5f));
    }
}

// ---------------- K2: normalize + transpose -> xnT[b][n][c] bf16 ------------
__global__ __launch_bounds__(256) void gn_norm_t(
    const float* __restrict__ x, const float* __restrict__ gamma,
    const float* __restrict__ beta, const float2* __restrict__ stats,
    unsigned short* __restrict__ xnT) {
    __shared__ unsigned short tile[64 * 72];  // [j][c], padded
    int t = threadIdx.x;
    int jt = blockIdx.x, ct = blockIdx.y, b = blockIdx.z;
    int c = t >> 2, jseg = (t & 3) * 16;
    float2 ms = stats[b * 8 + ct];            // 64-ch tiles align with groups
    int ch = ct * 64 + c;
    float g  = gamma[ch] * ms.y;
    float bb = beta[ch] - ms.x * g;
    const float* src = x + ((size_t)(b * 512 + ch)) * 1024 + jt * 64 + jseg;
    float4 v0 = *(const float4*)(src);
    float4 v1 = *(const float4*)(src + 4);
    float4 v2 = *(const float4*)(src + 8);
    float4 v3 = *(const float4*)(src + 12);
    float vv[16] = {v0.x,v0.y,v0.z,v0.w, v1.x,v1.y,v1.z,v1.w,
                    v2.x,v2.y,v2.z,v2.w, v3.x,v3.y,v3.z,v3.w};
    #pragma unroll
    for (int e = 0; e < 16; ++e)
        tile[(jseg + e) * 72 + c] = f2bf(fmaf(vv[e], g, bb));
    __syncthreads();
    int j = t >> 2, cseg = (t & 3) * 16;
    unsigned short* dst = xnT + ((size_t)b * 1024 + jt * 64 + j) * 512 + ct * 64 + cseg;
    bf16x8 a0 = *(const bf16x8*)&tile[j * 72 + cseg];
    bf16x8 a1 = *(const bf16x8*)&tile[j * 72 + cseg + 8];
    *(bf16x8*)dst = a0;
    *(bf16x8*)(dst + 8) = a1;
}

// ---------------- K3: QKV GEMM: qkv[b][o][j] = sum_c Wqkv[o][c] xn[b][c][j] -
// A = Wqkv bf16 [1536][512] row-major; B = xnT[b] [1024 j][512 c] row-major.
__global__ __launch_bounds__(256) void qkv_gemm(
    const unsigned short* __restrict__ W, const unsigned short* __restrict__ xnT,
    unsigned short* __restrict__ qkv) {
    __shared__ unsigned short a_t[128 * 72];  // [o][k]
    __shared__ unsigned short b_t[128 * 72];  // [j][k]
    int t = threadIdx.x, w = t >> 6, l = t & 63, lr = l & 15, lg = l >> 4;
    int jt = blockIdx.x, mt = blockIdx.y, b = blockIdx.z;
    int o0 = mt * 128, j0 = jt * 128;
    int wr = w >> 1, wc = w & 1;
    const unsigned short* Bsrc = xnT + (size_t)b * 1024 * 512;
    f32x4 acc[4][4] = {};
    int srow = t >> 1, sseg = (t & 1) * 32;
    for (int kk = 0; kk < 512; kk += 64) {
        const unsigned short* ga = W    + (size_t)(o0 + srow) * 512 + kk + sseg;
        const unsigned short* gb = Bsrc + (size_t)(j0 + srow) * 512 + kk + sseg;
        bf16x8 a0 = *(const bf16x8*)ga,        a1 = *(const bf16x8*)(ga + 8);
        bf16x8 a2 = *(const bf16x8*)(ga + 16), a3 = *(const bf16x8*)(ga + 24);
        bf16x8 c0 = *(const bf16x8*)gb,        c1 = *(const bf16x8*)(gb + 8);
        bf16x8 c2 = *(const bf16x8*)(gb + 16), c3 = *(const bf16x8*)(gb + 24);
        *(bf16x8*)&a_t[srow * 72 + sseg]      = a0;
        *(bf16x8*)&a_t[srow * 72 + sseg + 8]  = a1;
        *(bf16x8*)&a_t[srow * 72 + sseg + 16] = a2;
        *(bf16x8*)&a_t[srow * 72 + sseg + 24] = a3;
        *(bf16x8*)&b_t[srow * 72 + sseg]      = c0;
        *(bf16x8*)&b_t[srow * 72 + sseg + 8]  = c1;
        *(bf16x8*)&b_t[srow * 72 + sseg + 16] = c2;
        *(bf16x8*)&b_t[srow * 72 + sseg + 24] = c3;
        __syncthreads();
        #pragma unroll
        for (int ks = 0; ks < 2; ++ks) {
            bf16x8 af[4], bfr[4];
            #pragma unroll
            for (int m = 0; m < 4; ++m)
                af[m] = *(const bf16x8*)&a_t[(wr * 64 + m * 16 + lr) * 72 + ks * 32 + lg * 8];
            #pragma unroll
            for (int n = 0; n < 4; ++n)
                bfr[n] = *(const bf16x8*)&b_t[(wc * 64 + n * 16 + lr) * 72 + ks * 32 + lg * 8];
            #pragma unroll
            for (int m = 0; m < 4; ++m)
                #pragma unroll
                for (int n = 0; n < 4; ++n)
                    acc[m][n] = MFMA16(af[m], bfr[n], acc[m][n]);
        }
        __syncthreads();
    }
    #pragma unroll
    for (int m = 0; m < 4; ++m)
        #pragma unroll
        for (int n = 0; n < 4; ++n)
            #pragma unroll
            for (int r = 0; r < 4; ++r) {
                int o = o0 + wr * 64 + m * 16 + lg * 4 + r;
                int j = j0 + wc * 64 + n * 16 + lr;
                qkv[((size_t)b * 1536 + o) * 1024 + j] = f2bf(acc[m][n][r]);
            }
}

// ---------------- K4: flash attention per (b, h, qtile) ---------------------
// qkv rows: q = [0..511], k = [512..1023], v = [1024..1535]; per head 64 rows.
__global__ __launch_bounds__(256) void attn_kern(
    const unsigned short* __restrict__ qkv, unsigned short* __restrict__ o_t) {
    __shared__ unsigned short k_t[64 * 72];       // [j][dd]
    __shared__ unsigned short v_s[64 * 72];       // [dd][j]
    __shared__ unsigned short p_s[4 * 32 * 72];   // per-wave [i][j]
    int t = threadIdx.x, w = t >> 6, l = t & 63, lr = l & 15, lg = l >> 4;
    int qt = blockIdx.x, h = blockIdx.y, b = blockIdx.z;
    const unsigned short* qb = qkv + (size_t)(b * 1536 + h * 64) * 1024;
    const unsigned short* kb = qb + (size_t)512 * 1024;
    const unsigned short* vb = qb + (size_t)1024 * 1024;
    int i0 = qt * 128 + w * 32;

    // Q fragments direct from global (once): A[row=i][k=dd]
    bf16x8 aq[2][2];
    #pragma unroll
    for (int it = 0; it < 2; ++it)
        #pragma unroll
        for (int kt = 0; kt < 2; ++kt)
            #pragma unroll
            for (int e = 0; e < 8; ++e) {
                int dd = kt * 32 + lg * 8 + e;
                aq[it][kt][e] = (short)qb[(size_t)dd * 1024 + i0 + it * 16 + lr];
            }

    float m8[8], l8[8];
    #pragma unroll
    for (int i = 0; i < 8; ++i) { m8[i] = -3.0e38f; l8[i] = 0.f; }
    f32x4 acc[2][4] = {};
    unsigned short* pw = p_s + w * (32 * 72);

    int sdd = t >> 2, sjseg = (t & 3) * 16;
    for (int j0 = 0; j0 < 1024; j0 += 64) {
        // stage K (transposed) and V (direct)
        {
            const unsigned short* ks = kb + (size_t)sdd * 1024 + j0 + sjseg;
            const unsigned short* vs = vb + (size_t)sdd * 1024 + j0 + sjseg;
            bf16x8 k0 = *(const bf16x8*)ks, k1 = *(const bf16x8*)(ks + 8);
            bf16x8 u0 = *(const bf16x8*)vs, u1 = *(const bf16x8*)(vs + 8);
            #pragma unroll
            for (int e = 0; e < 8; ++e) {
                k_t[(sjseg + e) * 72 + sdd]     = k0[e];
                k_t[(sjseg + 8 + e) * 72 + sdd] = k1[e];
            }
            *(bf16x8*)&v_s[sdd * 72 + sjseg]     = u0;
            *(bf16x8*)&v_s[sdd * 72 + sjseg + 8] = u1;
        }
        __syncthreads();

        // S = (Q^T K) * scale
        f32x4 s[2][4] = {};
        #pragma unroll
        for (int kt = 0; kt < 2; ++kt) {
            bf16x8 bk[4];
            #pragma unroll
            for (int jt = 0; jt < 4; ++jt)
                bk[jt] = *(const bf16x8*)&k_t[(jt * 16 + lr) * 72 + kt * 32 + lg * 8];
            #pragma unroll
            for (int it = 0; it < 2; ++it)
                #pragma unroll
                for (int jt = 0; jt < 4; ++jt)
                    s[it][jt] = MFMA16(aq[it][kt], bk[jt], s[it][jt]);
        }
        #pragma unroll
        for (int it = 0; it < 2; ++it)
            #pragma unroll
            for (int jt = 0; jt < 4; ++jt)
                s[it][jt] *= 0.125f;   // dim_head^-0.5

        // online softmax (rows live at (lane>>4)*4+r, duplicated over lane&15)
        #pragma unroll
        for (int it = 0; it < 2; ++it)
            #pragma unroll
            for (int r = 0; r < 4; ++r) {
                int idx = it * 4 + r;
                float sm = fmaxf(fmaxf(s[it][0][r], s[it][1][r]),
                                 fmaxf(s[it][2][r], s[it][3][r]));
                sm = fmaxf(sm, __shfl_xor(sm, 1));
                sm = fmaxf(sm, __shfl_xor(sm, 2));
                sm = fmaxf(sm, __shfl_xor(sm, 4));
                sm = fmaxf(sm, __shfl_xor(sm, 8));
                float mo = m8[idx], mn = fmaxf(mo, sm);
                float al = __expf(mo - mn);
                float rs = 0.f;
                #pragma unroll
                for (int jt = 0; jt < 4; ++jt) {
                    float p = __expf(s[it][jt][r] - mn);
                    s[it][jt][r] = p; rs += p;
                }
                rs += __shfl_xor(rs, 1);
                rs += __shfl_xor(rs, 2);
                rs += __shfl_xor(rs, 4);
                rs += __shfl_xor(rs, 8);
                l8[idx] = l8[idx] * al + rs;
                m8[idx] = mn;
                #pragma unroll
                for (int dt = 0; dt < 4; ++dt) acc[it][dt][r] *= al;
            }

        // P -> wave-private LDS (bf16)
        #pragma unroll
        for (int it = 0; it < 2; ++it)
            #pragma unroll
            for (int jt = 0; jt < 4; ++jt)
                #pragma unroll
                for (int r = 0; r < 4; ++r)
                    pw[(it * 16 + lg * 4 + r) * 72 + jt * 16 + lr] = f2bf(s[it][jt][r]);

        // O += P V^T
        #pragma unroll
        for (int kj = 0; kj < 2; ++kj) {
            bf16x8 pa[2], bv[4];
            #pragma unroll
            for (int it = 0; it < 2; ++it)
                pa[it] = *(const bf16x8*)&pw[(it * 16 + lr) * 72 + kj * 32 + lg * 8];
            #pragma unroll
            for (int dt = 0; dt < 4; ++dt)
                bv[dt] = *(const bf16x8*)&v_s[(dt * 16 + lr) * 72 + kj * 32 + lg * 8];
            #pragma unroll
            for (int it = 0; it < 2; ++it)
                #pragma unroll
                for (int dt = 0; dt < 4; ++dt)
                    acc[it][dt] = MFMA16(pa[it], bv[dt], acc[it][dt]);
        }
        __syncthreads();
    }

    // epilogue: o_t[b][i][h*64+dd] = O[i][dd] / l  (bf16)
    #pragma unroll
    for (int it = 0; it < 2; ++it)
        #pragma unroll
        for (int dt = 0; dt < 4; ++dt)
            #pragma unroll
            for (int r = 0; r < 4; ++r) {
                float val = acc[it][dt][r] / l8[it * 4 + r];
                int i = i0 + it * 16 + lg * 4 + r;
                o_t[((size_t)b * 1024 + i) * 512 + h * 64 + dt * 16 + lr] = f2bf(val);
            }
}

// ---------------- K5: proj GEMM + bias + residual(xn) -----------------------
// out[b][o][j] = sum_c Wout[o][c] * u[c][j] + b_out[o] + xn[b][o][j]
// B = o_t[b] [1024 j][512 c] row-major.
__global__ __launch_bounds__(256) void proj_gemm(
    const unsigned short* __restrict__ W, const unsigned short* __restrict__ o_t,
    const float* __restrict__ b_out, const float* __restrict__ x,
    const float* __restrict__ gamma, const float* __restrict__ beta,
    const float2* __restrict__ stats, float* __restrict__ out) {
    __shared__ unsigned short a_t[128 * 72];
    __shared__ unsigned short b_t[128 * 72];
    int t = threadIdx.x, w = t >> 6, l = t & 63, lr = l & 15, lg = l >> 4;
    int jt = blockIdx.x, mt = blockIdx.y, b = blockIdx.z;
    int o0 = mt * 128, j0 = jt * 128;
    int wr = w >> 1, wc = w & 1;
    const unsigned short* Bsrc = o_t + (size_t)b * 1024 * 512;
    f32x4 acc[4][4] = {};
    int srow = t >> 1, sseg = (t & 1) * 32;
    for (int kk = 0; kk < 512; kk += 64) {
        const unsigned short* ga = W    + (size_t)(o0 + srow) * 512 + kk + sseg;
        const unsigned short* gb = Bsrc + (size_t)(j0 + srow) * 512 + kk + sseg;
        bf16x8 a0 = *(const bf16x8*)ga,        a1 = *(const bf16x8*)(ga + 8);
        bf16x8 a2 = *(const bf16x8*)(ga + 16), a3 = *(const bf16x8*)(ga + 24);
        bf16x8 c0 = *(const bf16x8*)gb,        c1 = *(const bf16x8*)(gb + 8);
        bf16x8 c2 = *(const bf16x8*)(gb + 16), c3 = *(const bf16x8*)(gb + 24);
        *(bf16x8*)&a_t[srow * 72 + sseg]      = a0;
        *(bf16x8*)&a_t[srow * 72 + sseg + 8]  = a1;
        *(bf16x8*)&a_t[srow * 72 + sseg + 16] = a2;
        *(bf16x8*)&a_t[srow * 72 + sseg + 24] = a3;
        *(bf16x8*)&b_t[srow * 72 + sseg]      = c0;
        *(bf16x8*)&b_t[srow * 72 + sseg + 8]  = c1;
        *(bf16x8*)&b_t[srow * 72 + sseg + 16] = c2;
        *(bf16x8*)&b_t[srow * 72 + sseg + 24] = c3;
        __syncthreads();
        #pragma unroll
        for (int ks = 0; ks < 2; ++ks) {
            bf16x8 af[4], bfr[4];
            #pragma unroll
            for (int m = 0; m < 4; ++m)
                af[m] = *(const bf16x8*)&a_t[(wr * 64 + m * 16 + lr) * 72 + ks * 32 + lg * 8];
            #pragma unroll
            for (int n = 0; n < 4; ++n)
                bfr[n] = *(const bf16x8*)&b_t[(wc * 64 + n * 16 + lr) * 72 + ks * 32 + lg * 8];
            #pragma unroll
            for (int m = 0; m < 4; ++m)
                #pragma unroll
                for (int n = 0; n < 4; ++n)
                    acc[m][n] = MFMA16(af[m], bfr[n], acc[m][n]);
        }
        __syncthreads();
    }
    #pragma unroll
    for (int m = 0; m < 4; ++m)
        #pragma unroll
        for (int r = 0; r < 4; ++r) {
            int o = o0 + wr * 64 + m * 16 + lg * 4 + r;
            float2 ms = stats[b * 8 + (o >> 6)];
            float g  = gamma[o] * ms.y;
            float bb = beta[o] - ms.x * g + b_out[o];
            const float* xr = x + ((size_t)b * 512 + o) * 1024;
            #pragma unroll
            for (int n = 0; n < 4; ++n) {
                int j = j0 + wc * 64 + n * 16 + lr;
                float xn = fmaf(xr[j], g, bb);
                out[((size_t)b * 512 + o) * 1024 + j] = acc[m][n][r] + xn;
            }
        }
}

// ---------------------------------------------------------------------------
extern "C" void kernel_launch(void* const* d_in, const int* in_sizes, int n_in,
                              void* d_out, int out_size, void* d_ws, size_t ws_size,
                              hipStream_t stream) {
    const float* x     = (const float*)d_in[0];
    const float* gamma = (const float*)d_in[1];
    const float* beta  = (const float*)d_in[2];
    const float* w_qkv = (const float*)d_in[3];
    const float* w_out = (const float*)d_in[4];
    const float* b_out = (const float*)d_in[5];
    float* out = (float*)d_out;

    char* ws = (char*)d_ws;
    unsigned short* wqb   = (unsigned short*)(ws);                    // 1,572,864 B
    unsigned short* wob   = (unsigned short*)(ws + 0x180000);         //   524,288 B
    float2*         stats = (float2*)(ws + 0x200000);                 //       512 B
    unsigned short* xnT   = (unsigned short*)(ws + 0x210000);         // 8,388,608 B
    unsigned short* qkv   = (unsigned short*)(ws + 0xA10000);         // 25,165,824 B
    unsigned short* o_t   = (unsigned short*)(ws + 0x2210000);        // 8,388,608 B
    // total ~44 MB

    cvt_weights<<<768, 256, 0, stream>>>(w_qkv, w_out, wqb, wob);
    gn_stats<<<64, 256, 0, stream>>>(x, stats);
    gn_norm_t<<<dim3(16, 8, 8), 256, 0, stream>>>(x, gamma, beta, stats, xnT);
    qkv_gemm<<<dim3(8, 12, 8), 256, 0, stream>>>(wqb, xnT, qkv);
    attn_kern<<<dim3(8, 8, 8), 256, 0, stream>>>(qkv, o_t);
    proj_gemm<<<dim3(8, 4, 8), 256, 0, stream>>>(wob, o_t, b_out, x, gamma, beta, stats, out);
}

// Round 3
// 126.038 us; speedup vs baseline: 1.1789x; 1.1789x over previous
//
#include <hip/hip_runtime.h>

// ---------------------------------------------------------------------------
// Fused: GroupNorm -> QKV (1x1 conv) -> 8-head attention (n=1024,d=64)
//        -> proj (1x1 conv) + bias + residual(xn)
// b=8, c=512, n=1024, GROUPS=8, HEADS=8, dim_head=64. bf16 MFMA, fp32 accum.
// R2: attention restructured — qT/kT/v layouts from QKV epilogue, 8-wave
//     blocks (16 rows/wave), reg-prefetch K/V, exp2-domain softmax, defer-max,
//     XCD-chunked swizzle.  R3: __exp2f -> __builtin_amdgcn_exp2f.
// ---------------------------------------------------------------------------

typedef short bf16x8 __attribute__((ext_vector_type(8)));
typedef float f32x4 __attribute__((ext_vector_type(4)));
typedef unsigned short u16x4 __attribute__((ext_vector_type(4)));

#define MFMA16(a, b, c) __builtin_amdgcn_mfma_f32_16x16x32_bf16(a, b, c, 0, 0, 0)
#define EXP2(x) __builtin_amdgcn_exp2f(x)

__device__ __forceinline__ unsigned short f2bf(float f) {
    unsigned u = __float_as_uint(f);
    u += 0x7fffu + ((u >> 16) & 1u);   // round-to-nearest-even
    return (unsigned short)(u >> 16);
}

// ---------------- K0: convert weights fp32 -> bf16 -------------------------
__global__ __launch_bounds__(256) void cvt_weights(
    const float* __restrict__ wq, const float* __restrict__ wo,
    unsigned short* __restrict__ wqb, unsigned short* __restrict__ wob) {
    int i = blockIdx.x * 256 + threadIdx.x;
    {
        float4 v = reinterpret_cast<const float4*>(wq)[i];
        unsigned short* d = wqb + (size_t)i * 4;
        d[0] = f2bf(v.x); d[1] = f2bf(v.y); d[2] = f2bf(v.z); d[3] = f2bf(v.w);
    }
    if (i < 65536) {
        float4 v = reinterpret_cast<const float4*>(wo)[i];
        unsigned short* d = wob + (size_t)i * 4;
        d[0] = f2bf(v.x); d[1] = f2bf(v.y); d[2] = f2bf(v.z); d[3] = f2bf(v.w);
    }
}

// ---------------- K1: groupnorm stats (mean, rstd) per (b,group) ------------
__global__ __launch_bounds__(256) void gn_stats(
    const float* __restrict__ x, float2* __restrict__ stats) {
    __shared__ float ss[256], sq[256];
    int bg = blockIdx.x, t = threadIdx.x;
    const float4* p = reinterpret_cast<const float4*>(x + (size_t)bg * 65536);
    float s = 0.f, q = 0.f;
    for (int i = t; i < 16384; i += 256) {
        float4 v = p[i];
        s += v.x + v.y + v.z + v.w;
        q += v.x * v.x + v.y * v.y + v.z * v.z + v.w * v.w;
    }
    ss[t] = s; sq[t] = q; __syncthreads();
    for (int o = 128; o > 0; o >>= 1) {
        if (t < o) { ss[t] += ss[t + o]; sq[t] += sq[t + o]; }
        __syncthreads();
    }
    if (t == 0) {
        float mean = ss[0] * (1.f / 65536.f);
        float var  = sq[0] * (1.f / 65536.f) - mean * mean;
        stats[bg] = make_float2(mean, rsqrtf(var + 1e-5f));
    }
}

// ---------------- K2: normalize + transpose -> xnT[b][n][c] bf16 ------------
__global__ __launch_bounds__(256) void gn_norm_t(
    const float* __restrict__ x, const float* __restrict__ gamma,
    const float* __restrict__ beta, const float2* __restrict__ stats,
    unsigned short* __restrict__ xnT) {
    __shared__ unsigned short tile[64 * 72];
    int t = threadIdx.x;
    int jt = blockIdx.x, ct = blockIdx.y, b = blockIdx.z;
    int c = t >> 2, jseg = (t & 3) * 16;
    float2 ms = stats[b * 8 + ct];
    int ch = ct * 64 + c;
    float g  = gamma[ch] * ms.y;
    float bb = beta[ch] - ms.x * g;
    const float* src = x + ((size_t)(b * 512 + ch)) * 1024 + jt * 64 + jseg;
    float4 v0 = *(const float4*)(src);
    float4 v1 = *(const float4*)(src + 4);
    float4 v2 = *(const float4*)(src + 8);
    float4 v3 = *(const float4*)(src + 12);
    float vv[16] = {v0.x,v0.y,v0.z,v0.w, v1.x,v1.y,v1.z,v1.w,
                    v2.x,v2.y,v2.z,v2.w, v3.x,v3.y,v3.z,v3.w};
    #pragma unroll
    for (int e = 0; e < 16; ++e)
        tile[(jseg + e) * 72 + c] = f2bf(fmaf(vv[e], g, bb));
    __syncthreads();
    int j = t >> 2, cseg = (t & 3) * 16;
    unsigned short* dst = xnT + ((size_t)b * 1024 + jt * 64 + j) * 512 + ct * 64 + cseg;
    bf16x8 a0 = *(const bf16x8*)&tile[j * 72 + cseg];
    bf16x8 a1 = *(const bf16x8*)&tile[j * 72 + cseg + 8];
    *(bf16x8*)dst = a0;
    *(bf16x8*)(dst + 8) = a1;
}

// ---------------- K3: QKV GEMM -> qT (scaled), kT, v ------------------------
// A = Wqkv bf16 [1536][512] row-major; B = xnT[b] [1024 j][512 c] row-major.
// qT,kT: [b*8+h][i/j][dd]  (dd contiguous);  v: [b*8+h][dd][j].
// Q pre-scaled by 0.125 * log2(e) so attention softmax runs in exp2 domain.
__global__ __launch_bounds__(256) void qkv_gemm(
    const unsigned short* __restrict__ W, const unsigned short* __restrict__ xnT,
    unsigned short* __restrict__ qT, unsigned short* __restrict__ kT,
    unsigned short* __restrict__ vK) {
    __shared__ unsigned short a_t[128 * 72];
    __shared__ unsigned short b_t[128 * 72];
    int t = threadIdx.x, w = t >> 6, l = t & 63, lr = l & 15, lg = l >> 4;
    int jt = blockIdx.x, mt = blockIdx.y, b = blockIdx.z;
    int o0 = mt * 128, j0 = jt * 128;
    int wr = w >> 1, wc = w & 1;
    const unsigned short* Bsrc = xnT + (size_t)b * 1024 * 512;
    f32x4 acc[4][4] = {};
    int srow = t >> 1, sseg = (t & 1) * 32;
    for (int kk = 0; kk < 512; kk += 64) {
        const unsigned short* ga = W    + (size_t)(o0 + srow) * 512 + kk + sseg;
        const unsigned short* gb = Bsrc + (size_t)(j0 + srow) * 512 + kk + sseg;
        bf16x8 a0 = *(const bf16x8*)ga,        a1 = *(const bf16x8*)(ga + 8);
        bf16x8 a2 = *(const bf16x8*)(ga + 16), a3 = *(const bf16x8*)(ga + 24);
        bf16x8 c0 = *(const bf16x8*)gb,        c1 = *(const bf16x8*)(gb + 8);
        bf16x8 c2 = *(const bf16x8*)(gb + 16), c3 = *(const bf16x8*)(gb + 24);
        *(bf16x8*)&a_t[srow * 72 + sseg]      = a0;
        *(bf16x8*)&a_t[srow * 72 + sseg + 8]  = a1;
        *(bf16x8*)&a_t[srow * 72 + sseg + 16] = a2;
        *(bf16x8*)&a_t[srow * 72 + sseg + 24] = a3;
        *(bf16x8*)&b_t[srow * 72 + sseg]      = c0;
        *(bf16x8*)&b_t[srow * 72 + sseg + 8]  = c1;
        *(bf16x8*)&b_t[srow * 72 + sseg + 16] = c2;
        *(bf16x8*)&b_t[srow * 72 + sseg + 24] = c3;
        __syncthreads();
        #pragma unroll
        for (int ks = 0; ks < 2; ++ks) {
            bf16x8 af[4], bfr[4];
            #pragma unroll
            for (int m = 0; m < 4; ++m)
                af[m] = *(const bf16x8*)&a_t[(wr * 64 + m * 16 + lr) * 72 + ks * 32 + lg * 8];
            #pragma unroll
            for (int n = 0; n < 4; ++n)
                bfr[n] = *(const bf16x8*)&b_t[(wc * 64 + n * 16 + lr) * 72 + ks * 32 + lg * 8];
            #pragma unroll
            for (int m = 0; m < 4; ++m)
                #pragma unroll
                for (int n = 0; n < 4; ++n)
                    acc[m][n] = MFMA16(af[m], bfr[n], acc[m][n]);
        }
        __syncthreads();
    }
    int part = mt >> 2;                       // 0=q, 1=k, 2=v
    int hh = ((mt * 2) + wr) & 7;             // head for this wave-row half
    if (part < 2) {
        unsigned short* dst = (part == 0) ? qT : kT;
        float sc = (part == 0) ? 0.1803368801f : 1.0f;  // 0.125*log2(e)
        #pragma unroll
        for (int m = 0; m < 4; ++m)
            #pragma unroll
            for (int n = 0; n < 4; ++n) {
                int j = j0 + wc * 64 + n * 16 + lr;
                u16x4 pkt;
                pkt[0] = f2bf(acc[m][n][0] * sc);
                pkt[1] = f2bf(acc[m][n][1] * sc);
                pkt[2] = f2bf(acc[m][n][2] * sc);
                pkt[3] = f2bf(acc[m][n][3] * sc);
                *(u16x4*)&dst[(((size_t)(b * 8 + hh)) * 1024 + j) * 64 + m * 16 + lg * 4] = pkt;
            }
    } else {
        #pragma unroll
        for (int m = 0; m < 4; ++m)
            #pragma unroll
            for (int n = 0; n < 4; ++n)
                #pragma unroll
                for (int r = 0; r < 4; ++r) {
                    int dd = m * 16 + lg * 4 + r;
                    int j = j0 + wc * 64 + n * 16 + lr;
                    vK[(((size_t)(b * 8 + hh)) * 64 + dd) * 1024 + j] = f2bf(acc[m][n][r]);
                }
    }
}

// ---------------- K4: flash attention, 8 waves x 16 q-rows ------------------
__global__ __launch_bounds__(512, 4) void attn_kern(
    const unsigned short* __restrict__ qT, const unsigned short* __restrict__ kT,
    const unsigned short* __restrict__ vK, unsigned short* __restrict__ o_t) {
    __shared__ unsigned short k_t[64 * 72];       // [j][dd]
    __shared__ unsigned short v_s[64 * 72];       // [dd][j]
    __shared__ unsigned short p_s[8 * 16 * 72];   // per-wave [i][j]
    int t = threadIdx.x, w = t >> 6, l = t & 63, lr = l & 15, lg = l >> 4;
    // XCD-chunked swizzle: 8 consecutive decoded blocks (one bh) per XCD
    int id = blockIdx.x;
    int lin = (id & 7) * 64 + (id >> 3);
    int qt = lin & 7, h = (lin >> 3) & 7, b = lin >> 6;
    size_t bh = (size_t)(b * 8 + h);
    const unsigned short* qb = qT + bh * 1024 * 64;
    const unsigned short* kb = kT + bh * 1024 * 64;
    const unsigned short* vb = vK + bh * 64 * 1024;
    int i0 = qt * 128 + w * 16;

    // Q fragments: A[row=i=lr][k=dd], dd = kt*32 + lg*8 + e  (b128 loads)
    bf16x8 aq[2];
    #pragma unroll
    for (int kt = 0; kt < 2; ++kt)
        aq[kt] = *(const bf16x8*)&qb[(size_t)(i0 + lr) * 64 + kt * 32 + lg * 8];

    float m8[4], l8[4];
    #pragma unroll
    for (int r = 0; r < 4; ++r) { m8[r] = -3.0e38f; l8[r] = 0.f; }
    f32x4 acc[4] = {};
    unsigned short* pw = p_s + w * (16 * 72);

    // staging assignment: each thread one b128 for K and one for V
    const unsigned short* kg = kb + (size_t)(t >> 3) * 64 + (t & 7) * 8;
    const unsigned short* vg = vb + (size_t)(t >> 3) * 1024 + (t & 7) * 8;
    unsigned short* kw = &k_t[(t >> 3) * 72 + (t & 7) * 8];
    unsigned short* vw = &v_s[(t >> 3) * 72 + (t & 7) * 8];

    bf16x8 nk = *(const bf16x8*)kg;
    bf16x8 nv = *(const bf16x8*)vg;

    for (int tile = 0; tile < 16; ++tile) {
        __syncthreads();                       // prev tile reads complete
        *(bf16x8*)kw = nk;
        *(bf16x8*)vw = nv;
        if (tile < 15) {                       // prefetch next tile (overlaps compute)
            nk = *(const bf16x8*)(kg + (tile + 1) * 4096);
            nv = *(const bf16x8*)(vg + (tile + 1) * 64);
        }
        __syncthreads();                       // LDS visible

        // S = Q K^T  (already scaled into log2 domain via qT)
        f32x4 s[4] = {};
        #pragma unroll
        for (int kt = 0; kt < 2; ++kt) {
            bf16x8 bk[4];
            #pragma unroll
            for (int jt = 0; jt < 4; ++jt)
                bk[jt] = *(const bf16x8*)&k_t[(jt * 16 + lr) * 72 + kt * 32 + lg * 8];
            #pragma unroll
            for (int jt = 0; jt < 4; ++jt)
                s[jt] = MFMA16(aq[kt], bk[jt], s[jt]);
        }

        // online softmax in exp2 domain; rows i = lg*4 + r
        float sm[4];
        #pragma unroll
        for (int r = 0; r < 4; ++r) {
            float v0 = fmaxf(fmaxf(s[0][r], s[1][r]), fmaxf(s[2][r], s[3][r]));
            v0 = fmaxf(v0, __shfl_xor(v0, 1));
            v0 = fmaxf(v0, __shfl_xor(v0, 2));
            v0 = fmaxf(v0, __shfl_xor(v0, 4));
            v0 = fmaxf(v0, __shfl_xor(v0, 8));
            sm[r] = v0;
        }
        float g = fmaxf(fmaxf(sm[0] - m8[0], sm[1] - m8[1]),
                        fmaxf(sm[2] - m8[2], sm[3] - m8[3]));
        if (__any(g > 11.0f)) {                // defer-max: rescale only on growth
            #pragma unroll
            for (int r = 0; r < 4; ++r) {
                float mn = fmaxf(m8[r], sm[r]);
                float al = EXP2(m8[r] - mn);
                l8[r] *= al;
                #pragma unroll
                for (int dt = 0; dt < 4; ++dt) acc[dt][r] *= al;
                m8[r] = mn;
            }
        }
        #pragma unroll
        for (int r = 0; r < 4; ++r) {
            float rs = 0.f;
            #pragma unroll
            for (int jt = 0; jt < 4; ++jt) {
                float p = EXP2(s[jt][r] - m8[r]);
                s[jt][r] = p; rs += p;
            }
            rs += __shfl_xor(rs, 1);
            rs += __shfl_xor(rs, 2);
            rs += __shfl_xor(rs, 4);
            rs += __shfl_xor(rs, 8);
            l8[r] += rs;
        }

        // P -> wave-private LDS (bf16)
        #pragma unroll
        for (int jt = 0; jt < 4; ++jt)
            #pragma unroll
            for (int r = 0; r < 4; ++r)
                pw[(lg * 4 + r) * 72 + jt * 16 + lr] = f2bf(s[jt][r]);

        // O += P V^T
        #pragma unroll
        for (int kj = 0; kj < 2; ++kj) {
            bf16x8 pa = *(const bf16x8*)&pw[lr * 72 + kj * 32 + lg * 8];
            bf16x8 bv[4];
            #pragma unroll
            for (int dt = 0; dt < 4; ++dt)
                bv[dt] = *(const bf16x8*)&v_s[(dt * 16 + lr) * 72 + kj * 32 + lg * 8];
            #pragma unroll
            for (int dt = 0; dt < 4; ++dt)
                acc[dt] = MFMA16(pa, bv[dt], acc[dt]);
        }
    }

    // epilogue: o_t[b][i][h*64+dd] = O[i][dd] / l
    float inv[4];
    #pragma unroll
    for (int r = 0; r < 4; ++r) inv[r] = 1.0f / l8[r];
    #pragma unroll
    for (int dt = 0; dt < 4; ++dt)
        #pragma unroll
        for (int r = 0; r < 4; ++r) {
            int i = i0 + lg * 4 + r;
            o_t[((size_t)b * 1024 + i) * 512 + h * 64 + dt * 16 + lr] =
                f2bf(acc[dt][r] * inv[r]);
        }
}

// ---------------- K5: proj GEMM + bias + residual(xn) -----------------------
__global__ __launch_bounds__(256) void proj_gemm(
    const unsigned short* __restrict__ W, const unsigned short* __restrict__ o_t,
    const float* __restrict__ b_out, const float* __restrict__ x,
    const float* __restrict__ gamma, const float* __restrict__ beta,
    const float2* __restrict__ stats, float* __restrict__ out) {
    __shared__ unsigned short a_t[128 * 72];
    __shared__ unsigned short b_t[128 * 72];
    int t = threadIdx.x, w = t >> 6, l = t & 63, lr = l & 15, lg = l >> 4;
    int jt = blockIdx.x, mt = blockIdx.y, b = blockIdx.z;
    int o0 = mt * 128, j0 = jt * 128;
    int wr = w >> 1, wc = w & 1;
    const unsigned short* Bsrc = o_t + (size_t)b * 1024 * 512;
    f32x4 acc[4][4] = {};
    int srow = t >> 1, sseg = (t & 1) * 32;
    for (int kk = 0; kk < 512; kk += 64) {
        const unsigned short* ga = W    + (size_t)(o0 + srow) * 512 + kk + sseg;
        const unsigned short* gb = Bsrc + (size_t)(j0 + srow) * 512 + kk + sseg;
        bf16x8 a0 = *(const bf16x8*)ga,        a1 = *(const bf16x8*)(ga + 8);
        bf16x8 a2 = *(const bf16x8*)(ga + 16), a3 = *(const bf16x8*)(ga + 24);
        bf16x8 c0 = *(const bf16x8*)gb,        c1 = *(const bf16x8*)(gb + 8);
        bf16x8 c2 = *(const bf16x8*)(gb + 16), c3 = *(const bf16x8*)(gb + 24);
        *(bf16x8*)&a_t[srow * 72 + sseg]      = a0;
        *(bf16x8*)&a_t[srow * 72 + sseg + 8]  = a1;
        *(bf16x8*)&a_t[srow * 72 + sseg + 16] = a2;
        *(bf16x8*)&a_t[srow * 72 + sseg + 24] = a3;
        *(bf16x8*)&b_t[srow * 72 + sseg]      = c0;
        *(bf16x8*)&b_t[srow * 72 + sseg + 8]  = c1;
        *(bf16x8*)&b_t[srow * 72 + sseg + 16] = c2;
        *(bf16x8*)&b_t[srow * 72 + sseg + 24] = c3;
        __syncthreads();
        #pragma unroll
        for (int ks = 0; ks < 2; ++ks) {
            bf16x8 af[4], bfr[4];
            #pragma unroll
            for (int m = 0; m < 4; ++m)
                af[m] = *(const bf16x8*)&a_t[(wr * 64 + m * 16 + lr) * 72 + ks * 32 + lg * 8];
            #pragma unroll
            for (int n = 0; n < 4; ++n)
                bfr[n] = *(const bf16x8*)&b_t[(wc * 64 + n * 16 + lr) * 72 + ks * 32 + lg * 8];
            #pragma unroll
            for (int m = 0; m < 4; ++m)
                #pragma unroll
                for (int n = 0; n < 4; ++n)
                    acc[m][n] = MFMA16(af[m], bfr[n], acc[m][n]);
        }
        __syncthreads();
    }
    #pragma unroll
    for (int m = 0; m < 4; ++m)
        #pragma unroll
        for (int r = 0; r < 4; ++r) {
            int o = o0 + wr * 64 + m * 16 + lg * 4 + r;
            float2 ms = stats[b * 8 + (o >> 6)];
            float g  = gamma[o] * ms.y;
            float bb = beta[o] - ms.x * g + b_out[o];
            const float* xr = x + ((size_t)b * 512 + o) * 1024;
            #pragma unroll
            for (int n = 0; n < 4; ++n) {
                int j = j0 + wc * 64 + n * 16 + lr;
                float xn = fmaf(xr[j], g, bb);
                out[((size_t)b * 512 + o) * 1024 + j] = acc[m][n][r] + xn;
            }
        }
}

// ---------------------------------------------------------------------------
extern "C" void kernel_launch(void* const* d_in, const int* in_sizes, int n_in,
                              void* d_out, int out_size, void* d_ws, size_t ws_size,
                              hipStream_t stream) {
    const float* x     = (const float*)d_in[0];
    const float* gamma = (const float*)d_in[1];
    const float* beta  = (const float*)d_in[2];
    const float* w_qkv = (const float*)d_in[3];
    const float* w_out = (const float*)d_in[4];
    const float* b_out = (const float*)d_in[5];
    float* out = (float*)d_out;

    char* ws = (char*)d_ws;
    unsigned short* wqb   = (unsigned short*)(ws);                    // 1.5 MB
    unsigned short* wob   = (unsigned short*)(ws + 0x180000);         // 0.5 MB
    float2*         stats = (float2*)(ws + 0x200000);                 // 512 B
    unsigned short* xnT   = (unsigned short*)(ws + 0x210000);         // 8 MB
    unsigned short* qT    = (unsigned short*)(ws + 0xA10000);         // 8 MB
    unsigned short* kT    = (unsigned short*)(ws + 0x1210000);        // 8 MB
    unsigned short* vK    = (unsigned short*)(ws + 0x1A10000);        // 8 MB
    unsigned short* o_t   = (unsigned short*)(ws + 0x2210000);        // 8 MB
    // total ~44.1 MB

    cvt_weights<<<768, 256, 0, stream>>>(w_qkv, w_out, wqb, wob);
    gn_stats<<<64, 256, 0, stream>>>(x, stats);
    gn_norm_t<<<dim3(16, 8, 8), 256, 0, stream>>>(x, gamma, beta, stats, xnT);
    qkv_gemm<<<dim3(8, 12, 8), 256, 0, stream>>>(wqb, xnT, qT, kT, vK);
    attn_kern<<<512, 512, 0, stream>>>(qT, kT, vK, o_t);
    proj_gemm<<<dim3(8, 4, 8), 256, 0, stream>>>(wob, o_t, b_out, x, gamma, beta, stats, out);
}

// Round 4
// 114.850 us; speedup vs baseline: 1.2937x; 1.0974x over previous
//
#include <hip/hip_runtime.h>

// ---------------------------------------------------------------------------
// Fused: GroupNorm -> QKV (1x1 conv) -> 8-head attention (n=1024,d=64)
//        -> proj (1x1 conv) + bias + residual(xn)
// b=8, c=512, n=1024, GROUPS=8, HEADS=8, dim_head=64. bf16 MFMA, fp32 accum.
// R4: DPP row_ror softmax reductions (VALU, no ds_swizzle), 1024x256 attention
//     grid (4 waves x 16 rows), reg-prefetch staging, exp2-domain softmax.
// ---------------------------------------------------------------------------

typedef short bf16x8 __attribute__((ext_vector_type(8)));
typedef float f32x4 __attribute__((ext_vector_type(4)));
typedef unsigned short u16x4 __attribute__((ext_vector_type(4)));

#define MFMA16(a, b, c) __builtin_amdgcn_mfma_f32_16x16x32_bf16(a, b, c, 0, 0, 0)
#define EXP2(x) __builtin_amdgcn_exp2f(x)
// rotate-right by N within each 16-lane row (pure VALU DPP)
#define ROR16(v, N) __int_as_float(__builtin_amdgcn_mov_dpp(__float_as_int(v), 0x120 + (N), 0xF, 0xF, false))

__device__ __forceinline__ unsigned short f2bf(float f) {
    unsigned u = __float_as_uint(f);
    u += 0x7fffu + ((u >> 16) & 1u);   // round-to-nearest-even
    return (unsigned short)(u >> 16);
}

// ---------------- K0: convert weights fp32 -> bf16 -------------------------
__global__ __launch_bounds__(256) void cvt_weights(
    const float* __restrict__ wq, const float* __restrict__ wo,
    unsigned short* __restrict__ wqb, unsigned short* __restrict__ wob) {
    int i = blockIdx.x * 256 + threadIdx.x;
    {
        float4 v = reinterpret_cast<const float4*>(wq)[i];
        unsigned short* d = wqb + (size_t)i * 4;
        d[0] = f2bf(v.x); d[1] = f2bf(v.y); d[2] = f2bf(v.z); d[3] = f2bf(v.w);
    }
    if (i < 65536) {
        float4 v = reinterpret_cast<const float4*>(wo)[i];
        unsigned short* d = wob + (size_t)i * 4;
        d[0] = f2bf(v.x); d[1] = f2bf(v.y); d[2] = f2bf(v.z); d[3] = f2bf(v.w);
    }
}

// ---------------- K1: groupnorm stats (mean, rstd) per (b,group) ------------
__global__ __launch_bounds__(256) void gn_stats(
    const float* __restrict__ x, float2* __restrict__ stats) {
    __shared__ float ss[256], sq[256];
    int bg = blockIdx.x, t = threadIdx.x;
    const float4* p = reinterpret_cast<const float4*>(x + (size_t)bg * 65536);
    float s = 0.f, q = 0.f;
    for (int i = t; i < 16384; i += 256) {
        float4 v = p[i];
        s += v.x + v.y + v.z + v.w;
        q += v.x * v.x + v.y * v.y + v.z * v.z + v.w * v.w;
    }
    ss[t] = s; sq[t] = q; __syncthreads();
    for (int o = 128; o > 0; o >>= 1) {
        if (t < o) { ss[t] += ss[t + o]; sq[t] += sq[t + o]; }
        __syncthreads();
    }
    if (t == 0) {
        float mean = ss[0] * (1.f / 65536.f);
        float var  = sq[0] * (1.f / 65536.f) - mean * mean;
        stats[bg] = make_float2(mean, rsqrtf(var + 1e-5f));
    }
}

// ---------------- K2: normalize + transpose -> xnT[b][n][c] bf16 ------------
__global__ __launch_bounds__(256) void gn_norm_t(
    const float* __restrict__ x, const float* __restrict__ gamma,
    const float* __restrict__ beta, const float2* __restrict__ stats,
    unsigned short* __restrict__ xnT) {
    __shared__ unsigned short tile[64 * 72];
    int t = threadIdx.x;
    int jt = blockIdx.x, ct = blockIdx.y, b = blockIdx.z;
    int c = t >> 2, jseg = (t & 3) * 16;
    float2 ms = stats[b * 8 + ct];
    int ch = ct * 64 + c;
    float g  = gamma[ch] * ms.y;
    float bb = beta[ch] - ms.x * g;
    const float* src = x + ((size_t)(b * 512 + ch)) * 1024 + jt * 64 + jseg;
    float4 v0 = *(const float4*)(src);
    float4 v1 = *(const float4*)(src + 4);
    float4 v2 = *(const float4*)(src + 8);
    float4 v3 = *(const float4*)(src + 12);
    float vv[16] = {v0.x,v0.y,v0.z,v0.w, v1.x,v1.y,v1.z,v1.w,
                    v2.x,v2.y,v2.z,v2.w, v3.x,v3.y,v3.z,v3.w};
    #pragma unroll
    for (int e = 0; e < 16; ++e)
        tile[(jseg + e) * 72 + c] = f2bf(fmaf(vv[e], g, bb));
    __syncthreads();
    int j = t >> 2, cseg = (t & 3) * 16;
    unsigned short* dst = xnT + ((size_t)b * 1024 + jt * 64 + j) * 512 + ct * 64 + cseg;
    bf16x8 a0 = *(const bf16x8*)&tile[j * 72 + cseg];
    bf16x8 a1 = *(const bf16x8*)&tile[j * 72 + cseg + 8];
    *(bf16x8*)dst = a0;
    *(bf16x8*)(dst + 8) = a1;
}

// ---------------- K3: QKV GEMM -> qT (scaled), kT, v ------------------------
// A = Wqkv bf16 [1536][512] row-major; B = xnT[b] [1024 j][512 c] row-major.
// qT,kT: [b*8+h][i/j][dd]  (dd contiguous);  v: [b*8+h][dd][j].
// Q pre-scaled by 0.125 * log2(e) so attention softmax runs in exp2 domain.
__global__ __launch_bounds__(256) void qkv_gemm(
    const unsigned short* __restrict__ W, const unsigned short* __restrict__ xnT,
    unsigned short* __restrict__ qT, unsigned short* __restrict__ kT,
    unsigned short* __restrict__ vK) {
    __shared__ unsigned short a_t[128 * 72];
    __shared__ unsigned short b_t[128 * 72];
    int t = threadIdx.x, w = t >> 6, l = t & 63, lr = l & 15, lg = l >> 4;
    int jt = blockIdx.x, mt = blockIdx.y, b = blockIdx.z;
    int o0 = mt * 128, j0 = jt * 128;
    int wr = w >> 1, wc = w & 1;
    const unsigned short* Bsrc = xnT + (size_t)b * 1024 * 512;
    f32x4 acc[4][4] = {};
    int srow = t >> 1, sseg = (t & 1) * 32;
    for (int kk = 0; kk < 512; kk += 64) {
        const unsigned short* ga = W    + (size_t)(o0 + srow) * 512 + kk + sseg;
        const unsigned short* gb = Bsrc + (size_t)(j0 + srow) * 512 + kk + sseg;
        bf16x8 a0 = *(const bf16x8*)ga,        a1 = *(const bf16x8*)(ga + 8);
        bf16x8 a2 = *(const bf16x8*)(ga + 16), a3 = *(const bf16x8*)(ga + 24);
        bf16x8 c0 = *(const bf16x8*)gb,        c1 = *(const bf16x8*)(gb + 8);
        bf16x8 c2 = *(const bf16x8*)(gb + 16), c3 = *(const bf16x8*)(gb + 24);
        *(bf16x8*)&a_t[srow * 72 + sseg]      = a0;
        *(bf16x8*)&a_t[srow * 72 + sseg + 8]  = a1;
        *(bf16x8*)&a_t[srow * 72 + sseg + 16] = a2;
        *(bf16x8*)&a_t[srow * 72 + sseg + 24] = a3;
        *(bf16x8*)&b_t[srow * 72 + sseg]      = c0;
        *(bf16x8*)&b_t[srow * 72 + sseg + 8]  = c1;
        *(bf16x8*)&b_t[srow * 72 + sseg + 16] = c2;
        *(bf16x8*)&b_t[srow * 72 + sseg + 24] = c3;
        __syncthreads();
        #pragma unroll
        for (int ks = 0; ks < 2; ++ks) {
            bf16x8 af[4], bfr[4];
            #pragma unroll
            for (int m = 0; m < 4; ++m)
                af[m] = *(const bf16x8*)&a_t[(wr * 64 + m * 16 + lr) * 72 + ks * 32 + lg * 8];
            #pragma unroll
            for (int n = 0; n < 4; ++n)
                bfr[n] = *(const bf16x8*)&b_t[(wc * 64 + n * 16 + lr) * 72 + ks * 32 + lg * 8];
            #pragma unroll
            for (int m = 0; m < 4; ++m)
                #pragma unroll
                for (int n = 0; n < 4; ++n)
                    acc[m][n] = MFMA16(af[m], bfr[n], acc[m][n]);
        }
        __syncthreads();
    }
    int part = mt >> 2;                       // 0=q, 1=k, 2=v
    int hh = ((mt * 2) + wr) & 7;             // head for this wave-row half
    if (part < 2) {
        unsigned short* dst = (part == 0) ? qT : kT;
        float sc = (part == 0) ? 0.1803368801f : 1.0f;  // 0.125*log2(e)
        #pragma unroll
        for (int m = 0; m < 4; ++m)
            #pragma unroll
            for (int n = 0; n < 4; ++n) {
                int j = j0 + wc * 64 + n * 16 + lr;
                u16x4 pkt;
                pkt[0] = f2bf(acc[m][n][0] * sc);
                pkt[1] = f2bf(acc[m][n][1] * sc);
                pkt[2] = f2bf(acc[m][n][2] * sc);
                pkt[3] = f2bf(acc[m][n][3] * sc);
                *(u16x4*)&dst[(((size_t)(b * 8 + hh)) * 1024 + j) * 64 + m * 16 + lg * 4] = pkt;
            }
    } else {
        #pragma unroll
        for (int m = 0; m < 4; ++m)
            #pragma unroll
            for (int n = 0; n < 4; ++n)
                #pragma unroll
                for (int r = 0; r < 4; ++r) {
                    int dd = m * 16 + lg * 4 + r;
                    int j = j0 + wc * 64 + n * 16 + lr;
                    vK[(((size_t)(b * 8 + hh)) * 64 + dd) * 1024 + j] = f2bf(acc[m][n][r]);
                }
    }
}

// ---------------- K4: flash attention, 4 waves x 16 q-rows ------------------
__global__ __launch_bounds__(256, 4) void attn_kern(
    const unsigned short* __restrict__ qT, const unsigned short* __restrict__ kT,
    const unsigned short* __restrict__ vK, unsigned short* __restrict__ o_t) {
    __shared__ unsigned short k_t[64 * 72];       // [j][dd]
    __shared__ unsigned short v_s[64 * 72];       // [dd][j]
    __shared__ unsigned short p_s[4 * 16 * 72];   // per-wave [i][j]
    int t = threadIdx.x, w = t >> 6, l = t & 63, lr = l & 15, lg = (l >> 4) & 3;
    // XCD-chunked swizzle: 128 consecutive decoded blocks (2 bh) per XCD
    int id = blockIdx.x;
    int lin = (id & 7) * 128 + (id >> 3);
    int qt = lin & 15, bh = lin >> 4;
    int b = bh >> 3, h = bh & 7;
    const unsigned short* qb = qT + (size_t)bh * 1024 * 64;
    const unsigned short* kb = kT + (size_t)bh * 1024 * 64;
    const unsigned short* vb = vK + (size_t)bh * 64 * 1024;
    int i0 = qt * 64 + w * 16;

    // Q fragments: A[row=i=lr][k=dd], dd = kt*32 + lg*8 + e  (b128 loads)
    bf16x8 aq[2];
    #pragma unroll
    for (int kt = 0; kt < 2; ++kt)
        aq[kt] = *(const bf16x8*)&qb[(size_t)(i0 + lr) * 64 + kt * 32 + lg * 8];

    float m8[4], l8[4];
    #pragma unroll
    for (int r = 0; r < 4; ++r) { m8[r] = -3.0e38f; l8[r] = 0.f; }
    f32x4 acc[4] = {};
    unsigned short* pw = p_s + w * (16 * 72);

    // staging: thread t stages 32B of K and 32B of V per tile
    int srow = t >> 2, scol = (t & 3) * 16;
    const unsigned short* kg = kb + srow * 64 + scol;            // K row j=srow
    const unsigned short* vg = vb + (size_t)srow * 1024 + scol;  // V row dd=srow
    unsigned short* kw = &k_t[srow * 72 + scol];
    unsigned short* vw = &v_s[srow * 72 + scol];

    bf16x8 nk0 = *(const bf16x8*)kg,       nk1 = *(const bf16x8*)(kg + 8);
    bf16x8 nv0 = *(const bf16x8*)vg,       nv1 = *(const bf16x8*)(vg + 8);

    for (int tile = 0; tile < 16; ++tile) {
        __syncthreads();                       // prev tile reads complete
        *(bf16x8*)kw = nk0; *(bf16x8*)(kw + 8) = nk1;
        *(bf16x8*)vw = nv0; *(bf16x8*)(vw + 8) = nv1;
        if (tile < 15) {                       // prefetch next tile
            const unsigned short* kn = kg + (tile + 1) * 4096;
            const unsigned short* vn = vg + (tile + 1) * 64;
            nk0 = *(const bf16x8*)kn; nk1 = *(const bf16x8*)(kn + 8);
            nv0 = *(const bf16x8*)vn; nv1 = *(const bf16x8*)(vn + 8);
        }
        __syncthreads();                       // LDS visible

        // S = Q K^T  (already scaled into log2 domain via qT)
        f32x4 s[4] = {};
        #pragma unroll
        for (int kt = 0; kt < 2; ++kt) {
            bf16x8 bk[4];
            #pragma unroll
            for (int jt = 0; jt < 4; ++jt)
                bk[jt] = *(const bf16x8*)&k_t[(jt * 16 + lr) * 72 + kt * 32 + lg * 8];
            #pragma unroll
            for (int jt = 0; jt < 4; ++jt)
                s[jt] = MFMA16(aq[kt], bk[jt], s[jt]);
        }

        // online softmax in exp2 domain; rows i = lg*4 + r
        float sm[4];
        #pragma unroll
        for (int r = 0; r < 4; ++r) {
            float v0 = fmaxf(fmaxf(s[0][r], s[1][r]), fmaxf(s[2][r], s[3][r]));
            v0 = fmaxf(v0, ROR16(v0, 1));
            v0 = fmaxf(v0, ROR16(v0, 2));
            v0 = fmaxf(v0, ROR16(v0, 4));
            v0 = fmaxf(v0, ROR16(v0, 8));
            sm[r] = v0;
        }
        float g = fmaxf(fmaxf(sm[0] - m8[0], sm[1] - m8[1]),
                        fmaxf(sm[2] - m8[2], sm[3] - m8[3]));
        if (__any(g > 11.0f)) {                // defer-max: rescale only on growth
            #pragma unroll
            for (int r = 0; r < 4; ++r) {
                float mn = fmaxf(m8[r], sm[r]);
                float al = EXP2(m8[r] - mn);
                l8[r] *= al;
                #pragma unroll
                for (int dt = 0; dt < 4; ++dt) acc[dt][r] *= al;
                m8[r] = mn;
            }
        }
        #pragma unroll
        for (int r = 0; r < 4; ++r) {
            float rs = 0.f;
            #pragma unroll
            for (int jt = 0; jt < 4; ++jt) {
                float p = EXP2(s[jt][r] - m8[r]);
                s[jt][r] = p; rs += p;
            }
            rs += ROR16(rs, 1);
            rs += ROR16(rs, 2);
            rs += ROR16(rs, 4);
            rs += ROR16(rs, 8);
            l8[r] += rs;
        }

        // P -> wave-private LDS (bf16)
        #pragma unroll
        for (int jt = 0; jt < 4; ++jt)
            #pragma unroll
            for (int r = 0; r < 4; ++r)
                pw[(lg * 4 + r) * 72 + jt * 16 + lr] = f2bf(s[jt][r]);

        // O += P V^T
        #pragma unroll
        for (int kj = 0; kj < 2; ++kj) {
            bf16x8 pa = *(const bf16x8*)&pw[lr * 72 + kj * 32 + lg * 8];
            bf16x8 bv[4];
            #pragma unroll
            for (int dt = 0; dt < 4; ++dt)
                bv[dt] = *(const bf16x8*)&v_s[(dt * 16 + lr) * 72 + kj * 32 + lg * 8];
            #pragma unroll
            for (int dt = 0; dt < 4; ++dt)
                acc[dt] = MFMA16(pa, bv[dt], acc[dt]);
        }
    }

    // epilogue: o_t[b][i][h*64+dd] = O[i][dd] / l
    float inv[4];
    #pragma unroll
    for (int r = 0; r < 4; ++r) inv[r] = 1.0f / l8[r];
    #pragma unroll
    for (int dt = 0; dt < 4; ++dt)
        #pragma unroll
        for (int r = 0; r < 4; ++r) {
            int i = i0 + lg * 4 + r;
            o_t[((size_t)b * 1024 + i) * 512 + h * 64 + dt * 16 + lr] =
                f2bf(acc[dt][r] * inv[r]);
        }
}

// ---------------- K5: proj GEMM + bias + residual(xn) -----------------------
__global__ __launch_bounds__(256) void proj_gemm(
    const unsigned short* __restrict__ W, const unsigned short* __restrict__ o_t,
    const float* __restrict__ b_out, const float* __restrict__ x,
    const float* __restrict__ gamma, const float* __restrict__ beta,
    const float2* __restrict__ stats, float* __restrict__ out) {
    __shared__ unsigned short a_t[128 * 72];
    __shared__ unsigned short b_t[128 * 72];
    int t = threadIdx.x, w = t >> 6, l = t & 63, lr = l & 15, lg = l >> 4;
    int jt = blockIdx.x, mt = blockIdx.y, b = blockIdx.z;
    int o0 = mt * 128, j0 = jt * 128;
    int wr = w >> 1, wc = w & 1;
    const unsigned short* Bsrc = o_t + (size_t)b * 1024 * 512;
    f32x4 acc[4][4] = {};
    int srow = t >> 1, sseg = (t & 1) * 32;
    for (int kk = 0; kk < 512; kk += 64) {
        const unsigned short* ga = W    + (size_t)(o0 + srow) * 512 + kk + sseg;
        const unsigned short* gb = Bsrc + (size_t)(j0 + srow) * 512 + kk + sseg;
        bf16x8 a0 = *(const bf16x8*)ga,        a1 = *(const bf16x8*)(ga + 8);
        bf16x8 a2 = *(const bf16x8*)(ga + 16), a3 = *(const bf16x8*)(ga + 24);
        bf16x8 c0 = *(const bf16x8*)gb,        c1 = *(const bf16x8*)(gb + 8);
        bf16x8 c2 = *(const bf16x8*)(gb + 16), c3 = *(const bf16x8*)(gb + 24);
        *(bf16x8*)&a_t[srow * 72 + sseg]      = a0;
        *(bf16x8*)&a_t[srow * 72 + sseg + 8]  = a1;
        *(bf16x8*)&a_t[srow * 72 + sseg + 16] = a2;
        *(bf16x8*)&a_t[srow * 72 + sseg + 24] = a3;
        *(bf16x8*)&b_t[srow * 72 + sseg]      = c0;
        *(bf16x8*)&b_t[srow * 72 + sseg + 8]  = c1;
        *(bf16x8*)&b_t[srow * 72 + sseg + 16] = c2;
        *(bf16x8*)&b_t[srow * 72 + sseg + 24] = c3;
        __syncthreads();
        #pragma unroll
        for (int ks = 0; ks < 2; ++ks) {
            bf16x8 af[4], bfr[4];
            #pragma unroll
            for (int m = 0; m < 4; ++m)
                af[m] = *(const bf16x8*)&a_t[(wr * 64 + m * 16 + lr) * 72 + ks * 32 + lg * 8];
            #pragma unroll
            for (int n = 0; n < 4; ++n)
                bfr[n] = *(const bf16x8*)&b_t[(wc * 64 + n * 16 + lr) * 72 + ks * 32 + lg * 8];
            #pragma unroll
            for (int m = 0; m < 4; ++m)
                #pragma unroll
                for (int n = 0; n < 4; ++n)
                    acc[m][n] = MFMA16(af[m], bfr[n], acc[m][n]);
        }
        __syncthreads();
    }
    #pragma unroll
    for (int m = 0; m < 4; ++m)
        #pragma unroll
        for (int r = 0; r < 4; ++r) {
            int o = o0 + wr * 64 + m * 16 + lg * 4 + r;
            float2 ms = stats[b * 8 + (o >> 6)];
            float g  = gamma[o] * ms.y;
            float bb = beta[o] - ms.x * g + b_out[o];
            const float* xr = x + ((size_t)b * 512 + o) * 1024;
            #pragma unroll
            for (int n = 0; n < 4; ++n) {
                int j = j0 + wc * 64 + n * 16 + lr;
                float xn = fmaf(xr[j], g, bb);
                out[((size_t)b * 512 + o) * 1024 + j] = acc[m][n][r] + xn;
            }
        }
}

// ---------------------------------------------------------------------------
extern "C" void kernel_launch(void* const* d_in, const int* in_sizes, int n_in,
                              void* d_out, int out_size, void* d_ws, size_t ws_size,
                              hipStream_t stream) {
    const float* x     = (const float*)d_in[0];
    const float* gamma = (const float*)d_in[1];
    const float* beta  = (const float*)d_in[2];
    const float* w_qkv = (const float*)d_in[3];
    const float* w_out = (const float*)d_in[4];
    const float* b_out = (const float*)d_in[5];
    float* out = (float*)d_out;

    char* ws = (char*)d_ws;
    unsigned short* wqb   = (unsigned short*)(ws);                    // 1.5 MB
    unsigned short* wob   = (unsigned short*)(ws + 0x180000);         // 0.5 MB
    float2*         stats = (float2*)(ws + 0x200000);                 // 512 B
    unsigned short* xnT   = (unsigned short*)(ws + 0x210000);         // 8 MB
    unsigned short* qT    = (unsigned short*)(ws + 0xA10000);         // 8 MB
    unsigned short* kT    = (unsigned short*)(ws + 0x1210000);        // 8 MB
    unsigned short* vK    = (unsigned short*)(ws + 0x1A10000);        // 8 MB
    unsigned short* o_t   = (unsigned short*)(ws + 0x2210000);        // 8 MB
    // total ~44.1 MB

    cvt_weights<<<768, 256, 0, stream>>>(w_qkv, w_out, wqb, wob);
    gn_stats<<<64, 256, 0, stream>>>(x, stats);
    gn_norm_t<<<dim3(16, 8, 8), 256, 0, stream>>>(x, gamma, beta, stats, xnT);
    qkv_gemm<<<dim3(8, 12, 8), 256, 0, stream>>>(wqb, xnT, qT, kT, vK);
    attn_kern<<<1024, 256, 0, stream>>>(qT, kT, vK, o_t);
    proj_gemm<<<dim3(8, 4, 8), 256, 0, stream>>>(wob, o_t, b_out, x, gamma, beta, stats, out);
}

// Round 7
// 111.946 us; speedup vs baseline: 1.3273x; 1.0259x over previous
//
#include <hip/hip_runtime.h>
#include <hip/hip_bf16.h>

// ---------------------------------------------------------------------------
// Fused: GroupNorm -> QKV (1x1 conv) -> 8-head attention (n=1024,d=64)
//        -> proj (1x1 conv) + bias + residual(xn)
// b=8, c=512, n=1024, GROUPS=8, HEADS=8, dim_head=64. bf16 MFMA, fp32 accum.
// R6: R4 base (proven deterministic) + row-sum via MFMA-ones column
//     (removes DPP sum chains) + P packing via __float22bfloat162_rn.
//     R7: bit_cast -> memcpy (bfloat162 not trivially copyable).
// ---------------------------------------------------------------------------

typedef short bf16x8 __attribute__((ext_vector_type(8)));
typedef float f32x4 __attribute__((ext_vector_type(4)));
typedef unsigned short u16x4 __attribute__((ext_vector_type(4)));

#define MFMA16(a, b, c) __builtin_amdgcn_mfma_f32_16x16x32_bf16(a, b, c, 0, 0, 0)
#define EXP2(x) __builtin_amdgcn_exp2f(x)
// rotate-right by N within each 16-lane row (pure VALU DPP)
#define ROR16(v, N) __int_as_float(__builtin_amdgcn_mov_dpp(__float_as_int(v), 0x120 + (N), 0xF, 0xF, false))

__device__ __forceinline__ unsigned short f2bf(float f) {
    unsigned u = __float_as_uint(f);
    u += 0x7fffu + ((u >> 16) & 1u);   // round-to-nearest-even
    return (unsigned short)(u >> 16);
}

// pack two fp32 -> u32 of two bf16 (lo=a, hi=b), RNE via HIP intrinsic
__device__ __forceinline__ unsigned pk2(float a, float b) {
    __hip_bfloat162 h = __float22bfloat162_rn(float2{a, b});
    unsigned r;
    __builtin_memcpy(&r, &h, 4);
    return r;
}

// ---------------- K0: convert weights fp32 -> bf16 -------------------------
__global__ __launch_bounds__(256) void cvt_weights(
    const float* __restrict__ wq, const float* __restrict__ wo,
    unsigned short* __restrict__ wqb, unsigned short* __restrict__ wob) {
    int i = blockIdx.x * 256 + threadIdx.x;
    {
        float4 v = reinterpret_cast<const float4*>(wq)[i];
        unsigned short* d = wqb + (size_t)i * 4;
        d[0] = f2bf(v.x); d[1] = f2bf(v.y); d[2] = f2bf(v.z); d[3] = f2bf(v.w);
    }
    if (i < 65536) {
        float4 v = reinterpret_cast<const float4*>(wo)[i];
        unsigned short* d = wob + (size_t)i * 4;
        d[0] = f2bf(v.x); d[1] = f2bf(v.y); d[2] = f2bf(v.z); d[3] = f2bf(v.w);
    }
}

// ---------------- K1: groupnorm stats (mean, rstd) per (b,group) ------------
__global__ __launch_bounds__(256) void gn_stats(
    const float* __restrict__ x, float2* __restrict__ stats) {
    __shared__ float ss[256], sq[256];
    int bg = blockIdx.x, t = threadIdx.x;
    const float4* p = reinterpret_cast<const float4*>(x + (size_t)bg * 65536);
    float s = 0.f, q = 0.f;
    for (int i = t; i < 16384; i += 256) {
        float4 v = p[i];
        s += v.x + v.y + v.z + v.w;
        q += v.x * v.x + v.y * v.y + v.z * v.z + v.w * v.w;
    }
    ss[t] = s; sq[t] = q; __syncthreads();
    for (int o = 128; o > 0; o >>= 1) {
        if (t < o) { ss[t] += ss[t + o]; sq[t] += sq[t + o]; }
        __syncthreads();
    }
    if (t == 0) {
        float mean = ss[0] * (1.f / 65536.f);
        float var  = sq[0] * (1.f / 65536.f) - mean * mean;
        stats[bg] = make_float2(mean, rsqrtf(var + 1e-5f));
    }
}

// ---------------- K2: normalize + transpose -> xnT[b][n][c] bf16 ------------
__global__ __launch_bounds__(256) void gn_norm_t(
    const float* __restrict__ x, const float* __restrict__ gamma,
    const float* __restrict__ beta, const float2* __restrict__ stats,
    unsigned short* __restrict__ xnT) {
    __shared__ unsigned short tile[64 * 72];
    int t = threadIdx.x;
    int jt = blockIdx.x, ct = blockIdx.y, b = blockIdx.z;
    int c = t >> 2, jseg = (t & 3) * 16;
    float2 ms = stats[b * 8 + ct];
    int ch = ct * 64 + c;
    float g  = gamma[ch] * ms.y;
    float bb = beta[ch] - ms.x * g;
    const float* src = x + ((size_t)(b * 512 + ch)) * 1024 + jt * 64 + jseg;
    float4 v0 = *(const float4*)(src);
    float4 v1 = *(const float4*)(src + 4);
    float4 v2 = *(const float4*)(src + 8);
    float4 v3 = *(const float4*)(src + 12);
    float vv[16] = {v0.x,v0.y,v0.z,v0.w, v1.x,v1.y,v1.z,v1.w,
                    v2.x,v2.y,v2.z,v2.w, v3.x,v3.y,v3.z,v3.w};
    #pragma unroll
    for (int e = 0; e < 16; ++e)
        tile[(jseg + e) * 72 + c] = f2bf(fmaf(vv[e], g, bb));
    __syncthreads();
    int j = t >> 2, cseg = (t & 3) * 16;
    unsigned short* dst = xnT + ((size_t)b * 1024 + jt * 64 + j) * 512 + ct * 64 + cseg;
    bf16x8 a0 = *(const bf16x8*)&tile[j * 72 + cseg];
    bf16x8 a1 = *(const bf16x8*)&tile[j * 72 + cseg + 8];
    *(bf16x8*)dst = a0;
    *(bf16x8*)(dst + 8) = a1;
}

// ---------------- K3: QKV GEMM -> qT (scaled), kT, v ------------------------
// A = Wqkv bf16 [1536][512] row-major; B = xnT[b] [1024 j][512 c] row-major.
// qT,kT: [b*8+h][i/j][dd]  (dd contiguous);  v: [b*8+h][dd][j].
// Q pre-scaled by 0.125 * log2(e) so attention softmax runs in exp2 domain.
__global__ __launch_bounds__(256) void qkv_gemm(
    const unsigned short* __restrict__ W, const unsigned short* __restrict__ xnT,
    unsigned short* __restrict__ qT, unsigned short* __restrict__ kT,
    unsigned short* __restrict__ vK) {
    __shared__ unsigned short a_t[128 * 72];
    __shared__ unsigned short b_t[128 * 72];
    int t = threadIdx.x, w = t >> 6, l = t & 63, lr = l & 15, lg = l >> 4;
    int jt = blockIdx.x, mt = blockIdx.y, b = blockIdx.z;
    int o0 = mt * 128, j0 = jt * 128;
    int wr = w >> 1, wc = w & 1;
    const unsigned short* Bsrc = xnT + (size_t)b * 1024 * 512;
    f32x4 acc[4][4] = {};
    int srow = t >> 1, sseg = (t & 1) * 32;
    for (int kk = 0; kk < 512; kk += 64) {
        const unsigned short* ga = W    + (size_t)(o0 + srow) * 512 + kk + sseg;
        const unsigned short* gb = Bsrc + (size_t)(j0 + srow) * 512 + kk + sseg;
        bf16x8 a0 = *(const bf16x8*)ga,        a1 = *(const bf16x8*)(ga + 8);
        bf16x8 a2 = *(const bf16x8*)(ga + 16), a3 = *(const bf16x8*)(ga + 24);
        bf16x8 c0 = *(const bf16x8*)gb,        c1 = *(const bf16x8*)(gb + 8);
        bf16x8 c2 = *(const bf16x8*)(gb + 16), c3 = *(const bf16x8*)(gb + 24);
        *(bf16x8*)&a_t[srow * 72 + sseg]      = a0;
        *(bf16x8*)&a_t[srow * 72 + sseg + 8]  = a1;
        *(bf16x8*)&a_t[srow * 72 + sseg + 16] = a2;
        *(bf16x8*)&a_t[srow * 72 + sseg + 24] = a3;
        *(bf16x8*)&b_t[srow * 72 + sseg]      = c0;
        *(bf16x8*)&b_t[srow * 72 + sseg + 8]  = c1;
        *(bf16x8*)&b_t[srow * 72 + sseg + 16] = c2;
        *(bf16x8*)&b_t[srow * 72 + sseg + 24] = c3;
        __syncthreads();
        #pragma unroll
        for (int ks = 0; ks < 2; ++ks) {
            bf16x8 af[4], bfr[4];
            #pragma unroll
            for (int m = 0; m < 4; ++m)
                af[m] = *(const bf16x8*)&a_t[(wr * 64 + m * 16 + lr) * 72 + ks * 32 + lg * 8];
            #pragma unroll
            for (int n = 0; n < 4; ++n)
                bfr[n] = *(const bf16x8*)&b_t[(wc * 64 + n * 16 + lr) * 72 + ks * 32 + lg * 8];
            #pragma unroll
            for (int m = 0; m < 4; ++m)
                #pragma unroll
                for (int n = 0; n < 4; ++n)
                    acc[m][n] = MFMA16(af[m], bfr[n], acc[m][n]);
        }
        __syncthreads();
    }
    int part = mt >> 2;                       // 0=q, 1=k, 2=v
    int hh = ((mt * 2) + wr) & 7;             // head for this wave-row half
    if (part < 2) {
        unsigned short* dst = (part == 0) ? qT : kT;
        float sc = (part == 0) ? 0.1803368801f : 1.0f;  // 0.125*log2(e)
        #pragma unroll
        for (int m = 0; m < 4; ++m)
            #pragma unroll
            for (int n = 0; n < 4; ++n) {
                int j = j0 + wc * 64 + n * 16 + lr;
                u16x4 pkt;
                pkt[0] = f2bf(acc[m][n][0] * sc);
                pkt[1] = f2bf(acc[m][n][1] * sc);
                pkt[2] = f2bf(acc[m][n][2] * sc);
                pkt[3] = f2bf(acc[m][n][3] * sc);
                *(u16x4*)&dst[(((size_t)(b * 8 + hh)) * 1024 + j) * 64 + m * 16 + lg * 4] = pkt;
            }
    } else {
        #pragma unroll
        for (int m = 0; m < 4; ++m)
            #pragma unroll
            for (int n = 0; n < 4; ++n)
                #pragma unroll
                for (int r = 0; r < 4; ++r) {
                    int dd = m * 16 + lg * 4 + r;
                    int j = j0 + wc * 64 + n * 16 + lr;
                    vK[(((size_t)(b * 8 + hh)) * 64 + dd) * 1024 + j] = f2bf(acc[m][n][r]);
                }
    }
}

// ---------------- K4: flash attention, 4 waves x 16 q-rows ------------------
// Online softmax with DPP max-reduce + defer-max; row-sum via MFMA against a
// ones B-operand (no cross-lane sum reduce).
__global__ __launch_bounds__(256, 4) void attn_kern(
    const unsigned short* __restrict__ qT, const unsigned short* __restrict__ kT,
    const unsigned short* __restrict__ vK, unsigned short* __restrict__ o_t) {
    __shared__ unsigned short k_t[64 * 72];       // [j][dd]
    __shared__ unsigned short v_s[64 * 72];       // [dd][j]
    __shared__ unsigned short p_s[4 * 16 * 72];   // per-wave [i][j]
    int t = threadIdx.x, w = t >> 6, l = t & 63, lr = l & 15, lg = (l >> 4) & 3;
    // XCD-chunked swizzle: 128 consecutive decoded blocks (2 bh) per XCD
    int id = blockIdx.x;
    int lin = (id & 7) * 128 + (id >> 3);
    int qt = lin & 15, bh = lin >> 4;
    int b = bh >> 3, h = bh & 7;
    const unsigned short* qb = qT + (size_t)bh * 1024 * 64;
    const unsigned short* kb = kT + (size_t)bh * 1024 * 64;
    const unsigned short* vb = vK + (size_t)bh * 64 * 1024;
    int i0 = qt * 64 + w * 16;

    // Q fragments: A[row=i=lr][k=dd], dd = kt*32 + lg*8 + e  (b128 loads)
    bf16x8 aq[2];
    #pragma unroll
    for (int kt = 0; kt < 2; ++kt)
        aq[kt] = *(const bf16x8*)&qb[(size_t)(i0 + lr) * 64 + kt * 32 + lg * 8];

    bf16x8 ones;
    #pragma unroll
    for (int e = 0; e < 8; ++e) ones[e] = (short)0x3F80;   // bf16 1.0

    float m8[4];
    #pragma unroll
    for (int r = 0; r < 4; ++r) m8[r] = -3.0e38f;
    f32x4 accO[4] = {};
    f32x4 accL = {};
    unsigned short* pw = p_s + w * (16 * 72);

    // staging: thread t stages 32B of K and 32B of V per tile
    int srow = t >> 2, scol = (t & 3) * 16;
    const unsigned short* kg = kb + srow * 64 + scol;            // K row j=srow
    const unsigned short* vg = vb + (size_t)srow * 1024 + scol;  // V row dd=srow
    unsigned short* kw = &k_t[srow * 72 + scol];
    unsigned short* vw = &v_s[srow * 72 + scol];

    bf16x8 nk0 = *(const bf16x8*)kg,       nk1 = *(const bf16x8*)(kg + 8);
    bf16x8 nv0 = *(const bf16x8*)vg,       nv1 = *(const bf16x8*)(vg + 8);

    for (int tile = 0; tile < 16; ++tile) {
        __syncthreads();                       // prev tile reads complete
        *(bf16x8*)kw = nk0; *(bf16x8*)(kw + 8) = nk1;
        *(bf16x8*)vw = nv0; *(bf16x8*)(vw + 8) = nv1;
        if (tile < 15) {                       // prefetch next tile
            const unsigned short* kn = kg + (tile + 1) * 4096;
            const unsigned short* vn = vg + (tile + 1) * 64;
            nk0 = *(const bf16x8*)kn; nk1 = *(const bf16x8*)(kn + 8);
            nv0 = *(const bf16x8*)vn; nv1 = *(const bf16x8*)(vn + 8);
        }
        __syncthreads();                       // LDS visible

        // S = Q K^T  (log2 domain)
        f32x4 s[4] = {};
        #pragma unroll
        for (int kt = 0; kt < 2; ++kt) {
            bf16x8 bk[4];
            #pragma unroll
            for (int jt = 0; jt < 4; ++jt)
                bk[jt] = *(const bf16x8*)&k_t[(jt * 16 + lr) * 72 + kt * 32 + lg * 8];
            #pragma unroll
            for (int jt = 0; jt < 4; ++jt)
                s[jt] = MFMA16(aq[kt], bk[jt], s[jt]);
        }

        // per-row tile max via DPP; defer-max: rescale only on growth
        float sm[4];
        #pragma unroll
        for (int r = 0; r < 4; ++r) {
            float v0 = fmaxf(fmaxf(s[0][r], s[1][r]), fmaxf(s[2][r], s[3][r]));
            v0 = fmaxf(v0, ROR16(v0, 1));
            v0 = fmaxf(v0, ROR16(v0, 2));
            v0 = fmaxf(v0, ROR16(v0, 4));
            v0 = fmaxf(v0, ROR16(v0, 8));
            sm[r] = v0;
        }
        float g = fmaxf(fmaxf(sm[0] - m8[0], sm[1] - m8[1]),
                        fmaxf(sm[2] - m8[2], sm[3] - m8[3]));
        if (__any(g > 11.0f)) {
            #pragma unroll
            for (int r = 0; r < 4; ++r) {
                float mn = fmaxf(m8[r], sm[r]);
                float al = EXP2(m8[r] - mn);
                accL[r] *= al;
                #pragma unroll
                for (int dt = 0; dt < 4; ++dt) accO[dt][r] *= al;
                m8[r] = mn;
            }
        }

        // P = exp2(S - m), pack to bf16 in wave-private LDS
        #pragma unroll
        for (int jt = 0; jt < 4; ++jt) {
            unsigned u01 = pk2(EXP2(s[jt][0] - m8[0]), EXP2(s[jt][1] - m8[1]));
            unsigned u23 = pk2(EXP2(s[jt][2] - m8[2]), EXP2(s[jt][3] - m8[3]));
            int col = jt * 16 + lr;
            pw[(lg * 4 + 0) * 72 + col] = (unsigned short)u01;
            pw[(lg * 4 + 1) * 72 + col] = (unsigned short)(u01 >> 16);
            pw[(lg * 4 + 2) * 72 + col] = (unsigned short)u23;
            pw[(lg * 4 + 3) * 72 + col] = (unsigned short)(u23 >> 16);
        }

        // O += P V^T ; L += P * 1  (row sums via matrix pipe)
        #pragma unroll
        for (int kj = 0; kj < 2; ++kj) {
            bf16x8 pa = *(const bf16x8*)&pw[lr * 72 + kj * 32 + lg * 8];
            accL = MFMA16(pa, ones, accL);
            bf16x8 bv[4];
            #pragma unroll
            for (int dt = 0; dt < 4; ++dt)
                bv[dt] = *(const bf16x8*)&v_s[(dt * 16 + lr) * 72 + kj * 32 + lg * 8];
            #pragma unroll
            for (int dt = 0; dt < 4; ++dt)
                accO[dt] = MFMA16(pa, bv[dt], accO[dt]);
        }
    }

    // epilogue: o_t[b][i][h*64+dd] = O[i][dd] / l
    float inv[4];
    #pragma unroll
    for (int r = 0; r < 4; ++r) inv[r] = 1.0f / accL[r];
    #pragma unroll
    for (int dt = 0; dt < 4; ++dt)
        #pragma unroll
        for (int r = 0; r < 4; ++r) {
            int i = i0 + lg * 4 + r;
            o_t[((size_t)b * 1024 + i) * 512 + h * 64 + dt * 16 + lr] =
                f2bf(accO[dt][r] * inv[r]);
        }
}

// ---------------- K5: proj GEMM + bias + residual(xn) -----------------------
__global__ __launch_bounds__(256) void proj_gemm(
    const unsigned short* __restrict__ W, const unsigned short* __restrict__ o_t,
    const float* __restrict__ b_out, const float* __restrict__ x,
    const float* __restrict__ gamma, const float* __restrict__ beta,
    const float2* __restrict__ stats, float* __restrict__ out) {
    __shared__ unsigned short a_t[128 * 72];
    __shared__ unsigned short b_t[128 * 72];
    int t = threadIdx.x, w = t >> 6, l = t & 63, lr = l & 15, lg = l >> 4;
    int jt = blockIdx.x, mt = blockIdx.y, b = blockIdx.z;
    int o0 = mt * 128, j0 = jt * 128;
    int wr = w >> 1, wc = w & 1;
    const unsigned short* Bsrc = o_t + (size_t)b * 1024 * 512;
    f32x4 acc[4][4] = {};
    int srow = t >> 1, sseg = (t & 1) * 32;
    for (int kk = 0; kk < 512; kk += 64) {
        const unsigned short* ga = W    + (size_t)(o0 + srow) * 512 + kk + sseg;
        const unsigned short* gb = Bsrc + (size_t)(j0 + srow) * 512 + kk + sseg;
        bf16x8 a0 = *(const bf16x8*)ga,        a1 = *(const bf16x8*)(ga + 8);
        bf16x8 a2 = *(const bf16x8*)(ga + 16), a3 = *(const bf16x8*)(ga + 24);
        bf16x8 c0 = *(const bf16x8*)gb,        c1 = *(const bf16x8*)(gb + 8);
        bf16x8 c2 = *(const bf16x8*)(gb + 16), c3 = *(const bf16x8*)(gb + 24);
        *(bf16x8*)&a_t[srow * 72 + sseg]      = a0;
        *(bf16x8*)&a_t[srow * 72 + sseg + 8]  = a1;
        *(bf16x8*)&a_t[srow * 72 + sseg + 16] = a2;
        *(bf16x8*)&a_t[srow * 72 + sseg + 24] = a3;
        *(bf16x8*)&b_t[srow * 72 + sseg]      = c0;
        *(bf16x8*)&b_t[srow * 72 + sseg + 8]  = c1;
        *(bf16x8*)&b_t[srow * 72 + sseg + 16] = c2;
        *(bf16x8*)&b_t[srow * 72 + sseg + 24] = c3;
        __syncthreads();
        #pragma unroll
        for (int ks = 0; ks < 2; ++ks) {
            bf16x8 af[4], bfr[4];
            #pragma unroll
            for (int m = 0; m < 4; ++m)
                af[m] = *(const bf16x8*)&a_t[(wr * 64 + m * 16 + lr) * 72 + ks * 32 + lg * 8];
            #pragma unroll
            for (int n = 0; n < 4; ++n)
                bfr[n] = *(const bf16x8*)&b_t[(wc * 64 + n * 16 + lr) * 72 + ks * 32 + lg * 8];
            #pragma unroll
            for (int m = 0; m < 4; ++m)
                #pragma unroll
                for (int n = 0; n < 4; ++n)
                    acc[m][n] = MFMA16(af[m], bfr[n], acc[m][n]);
        }
        __syncthreads();
    }
    #pragma unroll
    for (int m = 0; m < 4; ++m)
        #pragma unroll
        for (int r = 0; r < 4; ++r) {
            int o = o0 + wr * 64 + m * 16 + lg * 4 + r;
            float2 ms = stats[b * 8 + (o >> 6)];
            float g  = gamma[o] * ms.y;
            float bb = beta[o] - ms.x * g + b_out[o];
            const float* xr = x + ((size_t)b * 512 + o) * 1024;
            #pragma unroll
            for (int n = 0; n < 4; ++n) {
                int j = j0 + wc * 64 + n * 16 + lr;
                float xn = fmaf(xr[j], g, bb);
                out[((size_t)b * 512 + o) * 1024 + j] = acc[m][n][r] + xn;
            }
        }
}

// ---------------------------------------------------------------------------
extern "C" void kernel_launch(void* const* d_in, const int* in_sizes, int n_in,
                              void* d_out, int out_size, void* d_ws, size_t ws_size,
                              hipStream_t stream) {
    const float* x     = (const float*)d_in[0];
    const float* gamma = (const float*)d_in[1];
    const float* beta  = (const float*)d_in[2];
    const float* w_qkv = (const float*)d_in[3];
    const float* w_out = (const float*)d_in[4];
    const float* b_out = (const float*)d_in[5];
    float* out = (float*)d_out;

    char* ws = (char*)d_ws;
    unsigned short* wqb   = (unsigned short*)(ws);                    // 1.5 MB
    unsigned short* wob   = (unsigned short*)(ws + 0x180000);         // 0.5 MB
    float2*         stats = (float2*)(ws + 0x200000);                 // 512 B
    unsigned short* xnT   = (unsigned short*)(ws + 0x210000);         // 8 MB
    unsigned short* qT    = (unsigned short*)(ws + 0xA10000);         // 8 MB
    unsigned short* kT    = (unsigned short*)(ws + 0x1210000);        // 8 MB
    unsigned short* vK    = (unsigned short*)(ws + 0x1A10000);        // 8 MB
    unsigned short* o_t   = (unsigned short*)(ws + 0x2210000);        // 8 MB
    // total ~44.1 MB

    cvt_weights<<<768, 256, 0, stream>>>(w_qkv, w_out, wqb, wob);
    gn_stats<<<64, 256, 0, stream>>>(x, stats);
    gn_norm_t<<<dim3(16, 8, 8), 256, 0, stream>>>(x, gamma, beta, stats, xnT);
    qkv_gemm<<<dim3(8, 12, 8), 256, 0, stream>>>(wqb, xnT, qT, kT, vK);
    attn_kern<<<1024, 256, 0, stream>>>(qT, kT, vK, o_t);
    proj_gemm<<<dim3(8, 4, 8), 256, 0, stream>>>(wob, o_t, b_out, x, gamma, beta, stats, out);
}